// Round 1
// baseline (5488.506 us; speedup 1.0000x reference)
//
#include <hip/hip_runtime.h>
#include <hip/hip_bf16.h>

constexpr int KN   = 27;
constexpr int C1   = 32;
constexpr int C2   = 64;
constexpr int NCLS = 10;
constexpr float EPS = 1e-5f;

// ---------------------------------------------------------------------------
// K1: conv1 (2-stencil, 1->32ch) + bias + ReLU-folded segment-max-pool.
// One thread per particle, all 4 batches in registers (acc[4][32]).
// Weights transposed to LDS as wT[s][k][o] for float4 reads (2-addr broadcast).
// ---------------------------------------------------------------------------
__global__ __launch_bounds__(256) void k1_conv1_pool(
    const float* __restrict__ parts, const float* __restrict__ w1,
    const float* __restrict__ b1, const int* __restrict__ nbr1,
    const int* __restrict__ stencil1, const int* __restrict__ pool1,
    float* __restrict__ P1, int N, int N1)
{
  __shared__ float wT[2 * KN * C1];
  for (int i = threadIdx.x; i < 2 * KN * C1; i += blockDim.x) {
    int s = i / (KN * C1), r = i % (KN * C1), k = r / C1, o = r % C1;
    wT[i] = w1[(s * C1 + o) * KN + k];
  }
  __syncthreads();

  int n = blockIdx.x * blockDim.x + threadIdx.x;
  if (n >= N) return;

  int s = stencil1[n];
  const float* wbase = &wT[s * KN * C1];

  float acc[4][C1];
#pragma unroll
  for (int b = 0; b < 4; ++b)
#pragma unroll
    for (int o = 0; o < C1; ++o) acc[b][o] = 0.f;

  for (int k = 0; k < KN; ++k) {
    int j = nbr1[n * KN + k];
    float xv[4];
#pragma unroll
    for (int b = 0; b < 4; ++b) xv[b] = parts[(size_t)b * N + j];
    const float4* wr = (const float4*)&wbase[k * C1];
#pragma unroll
    for (int o4 = 0; o4 < C1 / 4; ++o4) {
      float4 w4 = wr[o4];
#pragma unroll
      for (int b = 0; b < 4; ++b) {
        acc[b][o4 * 4 + 0] = fmaf(w4.x, xv[b], acc[b][o4 * 4 + 0]);
        acc[b][o4 * 4 + 1] = fmaf(w4.y, xv[b], acc[b][o4 * 4 + 1]);
        acc[b][o4 * 4 + 2] = fmaf(w4.z, xv[b], acc[b][o4 * 4 + 2]);
        acc[b][o4 * 4 + 3] = fmaf(w4.w, xv[b], acc[b][o4 * 4 + 3]);
      }
    }
  }

  int p = pool1[n];
#pragma unroll
  for (int b = 0; b < 4; ++b) {
    float* dst = &P1[((size_t)b * N1 + p) * C1];
#pragma unroll
    for (int o = 0; o < C1; ++o) {
      float v = acc[b][o] + b1[o];
      if (v > 0.f) atomicMax((int*)&dst[o], __float_as_int(v));  // vals >= 0: int cmp == float cmp
    }
  }
}

// ---------------------------------------------------------------------------
// Per-channel sum & sumsq over a channel-last [.., C] fp32 buffer (float4 lanes)
// sums layout: [C sums][C sumsqs]
// ---------------------------------------------------------------------------
template <int C>
__global__ __launch_bounds__(256) void k_stats(
    const float* __restrict__ X, size_t nvec4, float* __restrict__ sums)
{
  __shared__ float ssum[2 * C];
  for (int i = threadIdx.x; i < 2 * C; i += blockDim.x) ssum[i] = 0.f;
  __syncthreads();

  size_t stride = (size_t)gridDim.x * blockDim.x;        // multiple of C/4
  size_t idx0 = (size_t)blockIdx.x * blockDim.x + threadIdx.x;
  int c4 = (int)(idx0 % (C / 4));                        // constant per thread
  const float4* Xv = (const float4*)X;

  float s4[4] = {0, 0, 0, 0}, q4[4] = {0, 0, 0, 0};
  for (size_t i = idx0; i < nvec4; i += stride) {
    float4 v = Xv[i];
    s4[0] += v.x; s4[1] += v.y; s4[2] += v.z; s4[3] += v.w;
    q4[0] += v.x * v.x; q4[1] += v.y * v.y; q4[2] += v.z * v.z; q4[3] += v.w * v.w;
  }
#pragma unroll
  for (int i = 0; i < 4; ++i) {
    atomicAdd(&ssum[c4 * 4 + i], s4[i]);
    atomicAdd(&ssum[C + c4 * 4 + i], q4[i]);
  }
  __syncthreads();
  for (int i = threadIdx.x; i < 2 * C; i += blockDim.x) atomicAdd(&sums[i], ssum[i]);
}

// ---------------------------------------------------------------------------
// K3: finalize BN1, fold into conv2 weights.
// w2t[k][c][o] = w2[o][c][k] * a1[c];  b2p[o] = b2[o] + sum_{c,k} w2[o,c,k]*d1[c]
// ---------------------------------------------------------------------------
__global__ void k3_prep2(const float* __restrict__ sums1,
                         const float* __restrict__ w2, const float* __restrict__ b2,
                         const float* __restrict__ g1, const float* __restrict__ beta1,
                         float Minv, float* __restrict__ w2t, float* __restrict__ b2p)
{
  __shared__ float a1[C1], d1[C1];
  int t = threadIdx.x;
  if (t < C1) {
    float mu = sums1[t] * Minv;
    float var = sums1[C1 + t] * Minv - mu * mu;
    float a = g1[t] * rsqrtf(var + EPS);
    a1[t] = a; d1[t] = beta1[t] - a * mu;
  }
  __syncthreads();
  for (int i = t; i < KN * C1 * C2; i += blockDim.x) {
    int k = i / (C1 * C2), r = i % (C1 * C2), c = r / C2, o = r % C2;
    w2t[i] = w2[(o * C1 + c) * KN + k] * a1[c];
  }
  if (t < C2) {
    float s = b2[t];
    for (int c = 0; c < C1; ++c) {
      float ws = 0.f;
      for (int k = 0; k < KN; ++k) ws += w2[(t * C1 + c) * KN + k];
      s += ws * d1[c];
    }
    b2p[t] = s;
  }
}

// ---------------------------------------------------------------------------
// K4: conv2 (32->64) + bias + ReLU-folded pool2. Thread = (particle, batch-pair).
// Weights read via thread-uniform addresses -> scalar loads feeding v_fma.
// P1 is [b][n1][32] channel-last so each neighbor is a 128B contiguous row.
// ---------------------------------------------------------------------------
__global__ __launch_bounds__(256) void k4_conv2_pool(
    const float* __restrict__ P1, const float* __restrict__ w2t,
    const float* __restrict__ b2p, const int* __restrict__ nbr2,
    const int* __restrict__ pool2, float* __restrict__ P2, int N1, int N2)
{
  int t = blockIdx.x * blockDim.x + threadIdx.x;
  int n = t >> 1;
  if (n >= N1) return;
  int bh = t & 1;  // batches 2*bh, 2*bh+1

  float acc0[C2], acc1[C2];
#pragma unroll
  for (int o = 0; o < C2; ++o) { acc0[o] = 0.f; acc1[o] = 0.f; }

  const float4* P1v = (const float4*)P1;
  for (int k = 0; k < KN; ++k) {
    int j = nbr2[n * KN + k];
    size_t base0 = ((size_t)(2 * bh) * N1 + j) * (C1 / 4);
    size_t base1 = base0 + (size_t)N1 * (C1 / 4);
#pragma unroll 1
    for (int cc = 0; cc < 4; ++cc) {  // 8 channels per chunk
      float4 a0 = P1v[base0 + cc * 2], a1v = P1v[base0 + cc * 2 + 1];
      float4 b0 = P1v[base1 + cc * 2], b1v = P1v[base1 + cc * 2 + 1];
      float xa[8] = {a0.x, a0.y, a0.z, a0.w, a1v.x, a1v.y, a1v.z, a1v.w};
      float xb[8] = {b0.x, b0.y, b0.z, b0.w, b1v.x, b1v.y, b1v.z, b1v.w};
#pragma unroll
      for (int c = 0; c < 8; ++c) {
        const float* wrow = &w2t[(k * C1 + cc * 8 + c) * C2];  // uniform -> s_load
#pragma unroll
        for (int o = 0; o < C2; ++o) {
          float w = wrow[o];
          acc0[o] = fmaf(w, xa[c], acc0[o]);
          acc1[o] = fmaf(w, xb[c], acc1[o]);
        }
      }
    }
  }

  int p = pool2[n];
  size_t d0 = ((size_t)(2 * bh) * N2 + p) * C2;
  size_t d1 = d0 + (size_t)N2 * C2;
#pragma unroll
  for (int o = 0; o < C2; ++o) {
    float v0 = acc0[o] + b2p[o];
    if (v0 > 0.f) atomicMax((int*)&P2[d0 + o], __float_as_int(v0));
    float v1 = acc1[o] + b2p[o];
    if (v1 > 0.f) atomicMax((int*)&P2[d1 + o], __float_as_int(v1));
  }
}

// ---------------------------------------------------------------------------
// K6: finalize BN2, fold into fc1: wfc1t[c][o] = wfc1[o][c]*a2[c]; bfc1p folded
// ---------------------------------------------------------------------------
__global__ void k6_prep3(const float* __restrict__ sums2,
                         const float* __restrict__ wfc1, const float* __restrict__ bfc1,
                         const float* __restrict__ g2, const float* __restrict__ beta2,
                         float Minv, float* __restrict__ wfc1t, float* __restrict__ bfc1p)
{
  __shared__ float a2[C2], d2[C2];
  int t = threadIdx.x;
  if (t < C2) {
    float mu = sums2[t] * Minv;
    float var = sums2[C2 + t] * Minv - mu * mu;
    float a = g2[t] * rsqrtf(var + EPS);
    a2[t] = a; d2[t] = beta2[t] - a * mu;
  }
  __syncthreads();
  for (int i = t; i < C2 * C2; i += blockDim.x) {
    int c = i / C2, o = i % C2;
    wfc1t[c * C2 + o] = wfc1[o * C2 + c] * a2[c];
  }
  if (t < C2) {
    float s = bfc1[t];
    for (int c = 0; c < C2; ++c) s += wfc1[t * C2 + c] * d2[c];
    bfc1p[t] = s;
  }
}

// ---------------------------------------------------------------------------
// K7: fc1 + ReLU, accumulate per-(b,o) sums of h and per-o sumsq (for BNfc).
// Block = 256 threads (4 waves), all same batch b = blockIdx.y. Wave-reduce
// then one atomicAdd per wave per channel. FC2+mean is deferred (linear).
// ---------------------------------------------------------------------------
__global__ __launch_bounds__(256) void k7_fc1(
    const float* __restrict__ P2, const float* __restrict__ wfc1t,
    const float* __restrict__ bfc1p, float* __restrict__ Hsum,
    float* __restrict__ Hsq, int N2)
{
  int b = blockIdx.y;
  int n = blockIdx.x * blockDim.x + threadIdx.x;
  bool valid = n < N2;

  const float4* Xv = (const float4*)&P2[((size_t)b * N2 + (valid ? n : 0)) * C2];
  float acc[C2];
#pragma unroll
  for (int o = 0; o < C2; ++o) acc[o] = 0.f;

#pragma unroll 1
  for (int c4 = 0; c4 < C2 / 4; ++c4) {
    float4 v = Xv[c4];
    float xs[4] = {v.x, v.y, v.z, v.w};
#pragma unroll
    for (int ci = 0; ci < 4; ++ci) {
      const float* wrow = &wfc1t[(c4 * 4 + ci) * C2];  // uniform -> s_load
#pragma unroll
      for (int o = 0; o < C2; ++o) acc[o] = fmaf(wrow[o], xs[ci], acc[o]);
    }
  }

  int lane = threadIdx.x & 63;
#pragma unroll 1
  for (int o = 0; o < C2; ++o) {
    float h = valid ? fmaxf(acc[o] + bfc1p[o], 0.f) : 0.f;
    float s = h, q = h * h;
#pragma unroll
    for (int d = 1; d < 64; d <<= 1) { s += __shfl_xor(s, d); q += __shfl_xor(q, d); }
    if (lane == 0) {
      atomicAdd(&Hsum[b * C2 + o], s);
      atomicAdd(&Hsq[o], q);
    }
  }
}

// ---------------------------------------------------------------------------
// K8: finalize BNfc, logits = wfc2 * (a*mean_n(h)+d) + bfc2, softmax -> out[4][10]
// ---------------------------------------------------------------------------
__global__ void k8_final(const float* __restrict__ Hsum, const float* __restrict__ Hsq,
                         const float* __restrict__ gfc, const float* __restrict__ betafc,
                         const float* __restrict__ wfc2, const float* __restrict__ bfc2,
                         int N2, float* __restrict__ out)
{
  __shared__ float pre[4 * C2];
  __shared__ float logits[4 * NCLS];
  int t = threadIdx.x;
  if (t < C2) {
    float S = 0.f;
#pragma unroll
    for (int b = 0; b < 4; ++b) S += Hsum[b * C2 + t];
    float M = 4.0f * (float)N2;
    float mu = S / M;
    float var = Hsq[t] / M - mu * mu;
    float a = gfc[t] * rsqrtf(var + EPS);
    float d = betafc[t] - a * mu;
    for (int b = 0; b < 4; ++b)
      pre[b * C2 + t] = a * (Hsum[b * C2 + t] / (float)N2) + d;
  }
  __syncthreads();
  if (t < 4 * NCLS) {
    int b = t / NCLS, i = t % NCLS;
    float s = bfc2[i];
    for (int o = 0; o < C2; ++o) s += wfc2[i * C2 + o] * pre[b * C2 + o];
    logits[t] = s;
  }
  __syncthreads();
  if (t < 4) {
    float m = -1e30f;
    for (int i = 0; i < NCLS; ++i) m = fmaxf(m, logits[t * NCLS + i]);
    float e[NCLS], sum = 0.f;
    for (int i = 0; i < NCLS; ++i) { e[i] = __expf(logits[t * NCLS + i] - m); sum += e[i]; }
    for (int i = 0; i < NCLS; ++i) out[t * NCLS + i] = e[i] / sum;
  }
}

extern "C" void kernel_launch(void* const* d_in, const int* in_sizes, int n_in,
                              void* d_out, int out_size, void* d_ws, size_t ws_size,
                              hipStream_t stream) {
  const float* parts   = (const float*)d_in[0];
  const float* w1      = (const float*)d_in[1];
  const float* b1      = (const float*)d_in[2];
  const float* w2      = (const float*)d_in[3];
  const float* b2      = (const float*)d_in[4];
  const float* wfc1    = (const float*)d_in[5];
  const float* bfc1    = (const float*)d_in[6];
  const float* wfc2    = (const float*)d_in[7];
  const float* bfc2    = (const float*)d_in[8];
  const float* g1      = (const float*)d_in[9];
  const float* beta1   = (const float*)d_in[10];
  const float* g2      = (const float*)d_in[11];
  const float* beta2   = (const float*)d_in[12];
  const float* gfc     = (const float*)d_in[13];
  const float* betafc  = (const float*)d_in[14];
  const int* nbr1      = (const int*)d_in[15];
  const int* stencil1  = (const int*)d_in[16];
  const int* pool1     = (const int*)d_in[17];
  const int* nbr2      = (const int*)d_in[18];
  const int* pool2     = (const int*)d_in[19];

  int N  = in_sizes[15] / KN;   // 1,000,000
  int N1 = in_sizes[18] / KN;   // 125,000
  int N2 = in_sizes[19] / 8;    // 15,625

  char* ws = (char*)d_ws;
  size_t szP1 = (size_t)4 * N1 * C1 * sizeof(float);   // 64 MB
  size_t szP2 = (size_t)4 * N2 * C2 * sizeof(float);   // 16 MB
  float* P1    = (float*)ws;
  float* P2    = (float*)(ws + szP1);
  float* sums1 = (float*)(ws + szP1 + szP2);           // 64 floats
  float* sums2 = sums1 + 64;                           // 128 floats
  float* Hsum  = sums2 + 128;                          // 256 floats
  float* Hsq   = Hsum + 256;                           // 64 floats
  size_t zbytes = szP1 + szP2 + (64 + 128 + 256 + 64) * sizeof(float);
  float* w2t   = Hsq + 64;                             // 27*32*64
  float* b2p   = w2t + KN * C1 * C2;                   // 64
  float* wfc1t = b2p + C2;                             // 64*64
  float* bfc1p = wfc1t + C2 * C2;                      // 64
  (void)ws_size; (void)n_in; (void)out_size;

  hipMemsetAsync(d_ws, 0, zbytes, stream);

  k1_conv1_pool<<<(N + 255) / 256, 256, 0, stream>>>(parts, w1, b1, nbr1, stencil1,
                                                     pool1, P1, N, N1);
  k_stats<C1><<<1024, 256, 0, stream>>>(P1, (size_t)4 * N1 * C1 / 4, sums1);
  k3_prep2<<<1, 256, 0, stream>>>(sums1, w2, b2, g1, beta1, 1.0f / (4.0f * N1), w2t, b2p);
  k4_conv2_pool<<<(2 * N1 + 255) / 256, 256, 0, stream>>>(P1, w2t, b2p, nbr2, pool2,
                                                          P2, N1, N2);
  k_stats<C2><<<512, 256, 0, stream>>>(P2, (size_t)4 * N2 * C2 / 4, sums2);
  k6_prep3<<<1, 256, 0, stream>>>(sums2, wfc1, bfc1, g2, beta2, 1.0f / (4.0f * N2),
                                  wfc1t, bfc1p);
  dim3 g7((N2 + 255) / 256, 4);
  k7_fc1<<<g7, 256, 0, stream>>>(P2, wfc1t, bfc1p, Hsum, Hsq, N2);
  k8_final<<<1, 64, 0, stream>>>(Hsum, Hsq, gfc, betafc, wfc2, bfc2, N2, (float*)d_out);
}